// Round 4
// baseline (482.946 us; speedup 1.0000x reference)
//
#include <hip/hip_runtime.h>

// ---------------------------------------------------------------------------
// MambaLatentBiMap: 2 branches (fwd / reversed) x 2 mamba layers + gates.
// Rows r = (j, b, l). Layer index for stage s, branch j: lidx = s + 2*j.
// Big GEMMs (gate, GEMM1, GEMM4) on MFMA with EXACT 3-way bf16 splitting:
// v = h + m + l (8 mantissa bits each, exact); product keeps 6 terms
// (hh, hm, mh, mm, hl, lh) -> fp32-equivalent precision.
// A operand split in-staging from f32; weights pre-split into 3 u16 planes.
// Scan: chunked linear recurrence (round-2 scheme).
// ---------------------------------------------------------------------------

#define LSEQ 1024
#define SCAN_CL 16
#define SCAN_NC 64
#define APAD 40   // LDS row stride in u16 (80 B): conflict-free frag reads

typedef short bf16x8 __attribute__((ext_vector_type(8)));
typedef float f32x4 __attribute__((ext_vector_type(4)));

__device__ __forceinline__ float sigmoidf_(float x) { return 1.f / (1.f + __expf(-x)); }
__device__ __forceinline__ float siluf_(float x)    { return x / (1.f + __expf(-x)); }
__device__ __forceinline__ float softplusf_(float x){ return x > 20.f ? x : log1pf(__expf(x)); }

__device__ __forceinline__ unsigned short bf16rne_(float v) {
  unsigned u = __float_as_uint(v);
  return (unsigned short)((u + 0x7FFFu + ((u >> 16) & 1u)) >> 16);
}
__device__ __forceinline__ float bfto_(unsigned short h) {
  return __uint_as_float(((unsigned)h) << 16);
}
__device__ __forceinline__ void split3_(float v, unsigned short& h,
                                        unsigned short& m, unsigned short& l) {
  h = bf16rne_(v); float r = v - bfto_(h);
  m = bf16rne_(r); float r2 = r - bfto_(m);
  l = bf16rne_(r2);
}

// ---------------- prep: x (B,D,L) -> X rows (j,b,l) cols d, j=1 reversed ---
__global__ __launch_bounds__(256) void prep_kernel(const float* __restrict__ x,
                                                   float* __restrict__ X0) {
  long idx = (long)blockIdx.x * 256 + threadIdx.x;   // 2,097,152
  int d = (int)(idx & 255);
  long t = idx >> 8;
  int l = (int)(t & 1023);
  int t2 = (int)(t >> 10);
  int b = t2 & 3;
  int j = t2 >> 2;
  int lsrc = j ? (1023 - l) : l;
  X0[idx] = x[((long)(b * 256 + d)) * LSEQ + lsrc];
}

// ---------------- Aneg = -exp(Alog) ----------------------------------------
__global__ __launch_bounds__(256) void aneg_kernel(const float* __restrict__ Alog,
                                                   float* __restrict__ Aneg) {
  int idx = blockIdx.x * 256 + threadIdx.x;          // 32768
  Aneg[idx] = -__expf(Alog[idx]);
}

// ---------------- elementwise 3-way split (Wg) -----------------------------
__global__ __launch_bounds__(256) void split3v_kernel(const float4* __restrict__ in,
                                                      ushort4* __restrict__ oh,
                                                      ushort4* __restrict__ om,
                                                      ushort4* __restrict__ ol, int n4) {
  int i = blockIdx.x * 256 + threadIdx.x;
  if (i >= n4) return;
  float4 v = in[i];
  ushort4 H, M, L;
  split3_(v.x, H.x, M.x, L.x); split3_(v.y, H.y, M.y, L.y);
  split3_(v.z, H.z, M.z, L.z); split3_(v.w, H.w, M.w, L.w);
  oh[i] = H; om[i] = M; ol[i] = L;
}

// ---------------- transpose + 3-way split: [Z][K][N] -> [Z][N][K] ----------
__global__ __launch_bounds__(256) void tconv3_kernel(const float* __restrict__ in,
                                                     unsigned short* __restrict__ oh,
                                                     unsigned short* __restrict__ om,
                                                     unsigned short* __restrict__ ol,
                                                     int K, int N) {
  __shared__ float T[32][33];
  int z = blockIdx.z;
  int n0 = blockIdx.x * 32, k0 = blockIdx.y * 32;
  int tx = threadIdx.x & 31, ty = threadIdx.x >> 5;   // 32 x 8
  const float* src = in + (long)z * K * N;
#pragma unroll
  for (int m = 0; m < 4; ++m)
    T[ty + 8 * m][tx] = src[(long)(k0 + ty + 8 * m) * N + n0 + tx];
  __syncthreads();
  long obase = (long)z * N * K;
#pragma unroll
  for (int m = 0; m < 4; ++m) {
    float v = T[tx][ty + 8 * m];
    long o = obase + (long)(n0 + ty + 8 * m) * K + k0 + tx;
    split3_(v, oh[o], om[o], ol[o]);
  }
}

// ---------------- MFMA 3-split bf16 GEMM -----------------------------------
// C[z](MxN) = A[z](MxK, f32) * B[z](NxK)^T (B pre-split 3 u16 planes).
// Tile 128x128x32, 4 waves (2x2), per-wave 64x64. A split in-staging.
// EPI: 0 plain f32 store, 1 sigmoid(bias + v).
template <int EPI>
__global__ __launch_bounds__(256, 1)
void gemm_mfma(const float* __restrict__ Ag, long aZ,
               const unsigned short* __restrict__ Bh_g,
               const unsigned short* __restrict__ Bm_g,
               const unsigned short* __restrict__ Bl_g, long bZ,
               const float* __restrict__ Bias, long biasZ,
               float* __restrict__ C, long cZ, int N, int K) {
  __shared__ unsigned short Ah[128 * APAD], Am[128 * APAD], Al[128 * APAD];
  __shared__ unsigned short Bh[128 * APAD], Bm[128 * APAD], Bl[128 * APAD];
  const int z = blockIdx.z;
  Ag += (long)z * aZ;
  const int m0 = blockIdx.y * 128, n0 = blockIdx.x * 128;
  const int tid = threadIdx.x;
  const int sr = tid >> 1, sh16 = (tid & 1) << 4;   // staging row, k-half
  const float* ga = Ag + (long)(m0 + sr) * K + sh16;
  const unsigned short* pbh = Bh_g + (long)z * bZ + (long)(n0 + sr) * K + sh16;
  const unsigned short* pbm = Bm_g + (long)z * bZ + (long)(n0 + sr) * K + sh16;
  const unsigned short* pbl = Bl_g + (long)z * bZ + (long)(n0 + sr) * K + sh16;
  const int lw = sr * APAD + sh16;

  const int lane = tid & 63, w = tid >> 6;
  const int wr = w >> 1, wc = w & 1;
  const int fr = lane & 15, koff = (lane >> 4) * 8;
  const int abase = (wr * 64 + fr) * APAD + koff;
  const int bbase = (wc * 64 + fr) * APAD + koff;

  f32x4 acc[4][4];
#pragma unroll
  for (int i = 0; i < 4; ++i)
#pragma unroll
    for (int j = 0; j < 4; ++j)
#pragma unroll
      for (int q = 0; q < 4; ++q) acc[i][j][q] = 0.f;

  float4 pa[4];
  uint4 pb[6];
  uint sa[3][8];

#pragma unroll
  for (int i = 0; i < 4; ++i) pa[i] = *(const float4*)(ga + 4 * i);
  pb[0] = *(const uint4*)(pbh); pb[1] = *(const uint4*)(pbh + 8);
  pb[2] = *(const uint4*)(pbm); pb[3] = *(const uint4*)(pbm + 8);
  pb[4] = *(const uint4*)(pbl); pb[5] = *(const uint4*)(pbl + 8);
#pragma unroll
  for (int i = 0; i < 4; ++i) {
    unsigned short h0, mm0, l0, h1, mm1, l1;
    split3_(pa[i].x, h0, mm0, l0); split3_(pa[i].y, h1, mm1, l1);
    sa[0][2*i]   = (uint)h0  | ((uint)h1  << 16);
    sa[1][2*i]   = (uint)mm0 | ((uint)mm1 << 16);
    sa[2][2*i]   = (uint)l0  | ((uint)l1  << 16);
    split3_(pa[i].z, h0, mm0, l0); split3_(pa[i].w, h1, mm1, l1);
    sa[0][2*i+1] = (uint)h0  | ((uint)h1  << 16);
    sa[1][2*i+1] = (uint)mm0 | ((uint)mm1 << 16);
    sa[2][2*i+1] = (uint)l0  | ((uint)l1  << 16);
  }

  for (int k0 = 0; k0 < K; k0 += 32) {
    __syncthreads();
    *(uint4*)(Ah + lw)     = make_uint4(sa[0][0], sa[0][1], sa[0][2], sa[0][3]);
    *(uint4*)(Ah + lw + 8) = make_uint4(sa[0][4], sa[0][5], sa[0][6], sa[0][7]);
    *(uint4*)(Am + lw)     = make_uint4(sa[1][0], sa[1][1], sa[1][2], sa[1][3]);
    *(uint4*)(Am + lw + 8) = make_uint4(sa[1][4], sa[1][5], sa[1][6], sa[1][7]);
    *(uint4*)(Al + lw)     = make_uint4(sa[2][0], sa[2][1], sa[2][2], sa[2][3]);
    *(uint4*)(Al + lw + 8) = make_uint4(sa[2][4], sa[2][5], sa[2][6], sa[2][7]);
    *(uint4*)(Bh + lw) = pb[0]; *(uint4*)(Bh + lw + 8) = pb[1];
    *(uint4*)(Bm + lw) = pb[2]; *(uint4*)(Bm + lw + 8) = pb[3];
    *(uint4*)(Bl + lw) = pb[4]; *(uint4*)(Bl + lw + 8) = pb[5];
    __syncthreads();
    const bool more = (k0 + 32 < K);
    if (more) {
      const int k1 = k0 + 32;
#pragma unroll
      for (int i = 0; i < 4; ++i) pa[i] = *(const float4*)(ga + k1 + 4 * i);
      pb[0] = *(const uint4*)(pbh + k1); pb[1] = *(const uint4*)(pbh + k1 + 8);
      pb[2] = *(const uint4*)(pbm + k1); pb[3] = *(const uint4*)(pbm + k1 + 8);
      pb[4] = *(const uint4*)(pbl + k1); pb[5] = *(const uint4*)(pbl + k1 + 8);
    }
    bf16x8 fbh[4], fbm[4], fbl[4];
#pragma unroll
    for (int nf = 0; nf < 4; ++nf) {
      fbh[nf] = *(const bf16x8*)(Bh + bbase + nf * (16 * APAD));
      fbm[nf] = *(const bf16x8*)(Bm + bbase + nf * (16 * APAD));
      fbl[nf] = *(const bf16x8*)(Bl + bbase + nf * (16 * APAD));
    }
#pragma unroll
    for (int mf = 0; mf < 4; ++mf) {
      bf16x8 fah = *(const bf16x8*)(Ah + abase + mf * (16 * APAD));
      bf16x8 fam = *(const bf16x8*)(Am + abase + mf * (16 * APAD));
      bf16x8 fal = *(const bf16x8*)(Al + abase + mf * (16 * APAD));
#pragma unroll
      for (int nf = 0; nf < 4; ++nf) {
        acc[mf][nf] = __builtin_amdgcn_mfma_f32_16x16x32_bf16(fah, fbh[nf], acc[mf][nf], 0, 0, 0);
        acc[mf][nf] = __builtin_amdgcn_mfma_f32_16x16x32_bf16(fah, fbm[nf], acc[mf][nf], 0, 0, 0);
        acc[mf][nf] = __builtin_amdgcn_mfma_f32_16x16x32_bf16(fam, fbh[nf], acc[mf][nf], 0, 0, 0);
        acc[mf][nf] = __builtin_amdgcn_mfma_f32_16x16x32_bf16(fam, fbm[nf], acc[mf][nf], 0, 0, 0);
        acc[mf][nf] = __builtin_amdgcn_mfma_f32_16x16x32_bf16(fah, fbl[nf], acc[mf][nf], 0, 0, 0);
        acc[mf][nf] = __builtin_amdgcn_mfma_f32_16x16x32_bf16(fal, fbh[nf], acc[mf][nf], 0, 0, 0);
      }
    }
    if (more) {
#pragma unroll
      for (int i = 0; i < 4; ++i) {
        unsigned short h0, mm0, l0, h1, mm1, l1;
        split3_(pa[i].x, h0, mm0, l0); split3_(pa[i].y, h1, mm1, l1);
        sa[0][2*i]   = (uint)h0  | ((uint)h1  << 16);
        sa[1][2*i]   = (uint)mm0 | ((uint)mm1 << 16);
        sa[2][2*i]   = (uint)l0  | ((uint)l1  << 16);
        split3_(pa[i].z, h0, mm0, l0); split3_(pa[i].w, h1, mm1, l1);
        sa[0][2*i+1] = (uint)h0  | ((uint)h1  << 16);
        sa[1][2*i+1] = (uint)mm0 | ((uint)mm1 << 16);
        sa[2][2*i+1] = (uint)l0  | ((uint)l1  << 16);
      }
    }
  }

  const float* bias = (EPI == 1) ? (Bias + (long)z * biasZ) : nullptr;
  float* Cz = C + (long)z * cZ;
#pragma unroll
  for (int mf = 0; mf < 4; ++mf)
#pragma unroll
    for (int nf = 0; nf < 4; ++nf) {
      int col = n0 + wc * 64 + nf * 16 + fr;
      int row0 = m0 + wr * 64 + mf * 16 + (lane >> 4) * 4;
#pragma unroll
      for (int q = 0; q < 4; ++q) {
        float v = acc[mf][nf][q];
        if (EPI == 1) v = sigmoidf_(v + bias[col]);
        Cz[(long)(row0 + q) * N + col] = v;
      }
    }
}

// ---------------- generic tiled fp32 GEMM (GEMM2, GEMM3) -------------------
template <int EPI>   // 0 none, 1 bias+softplus
__global__ __launch_bounds__(256)
void gemm_f32(const float* __restrict__ A, int lda, long aZ,
              const float* __restrict__ W, int ldw, long wZ,
              const float* __restrict__ Bias, long bZ,
              float* __restrict__ C, int ldc, long cZ,
              int M, int N, int K) {
  constexpr int BM = 128, BN = 64, BK = 16;
  __shared__ __align__(16) float As[BK][BM];
  __shared__ __align__(16) float Bs[BK][BN];
  const int z = blockIdx.z;
  A += (long)z * aZ;
  W += (long)z * wZ;
  C += (long)z * cZ;
  const float* bias = (EPI != 0) ? (Bias + (long)z * bZ) : nullptr;
  const int m0 = blockIdx.y * BM, n0 = blockIdx.x * BN;
  const int tid = threadIdx.x;
  const int tx = tid & 15, ty = tid >> 4;

  float acc[8][4];
#pragma unroll
  for (int i = 0; i < 8; ++i)
#pragma unroll
    for (int jn = 0; jn < 4; ++jn) acc[i][jn] = 0.f;

  for (int k0 = 0; k0 < K; k0 += BK) {
#pragma unroll
    for (int i = 0; i < 2; ++i) {
      int idx = tid + i * 256;
      int m = idx >> 2, k4 = (idx & 3) << 2;
      float4 v = *(const float4*)(A + (long)(m0 + m) * lda + k0 + k4);
      As[k4 + 0][m] = v.x; As[k4 + 1][m] = v.y;
      As[k4 + 2][m] = v.z; As[k4 + 3][m] = v.w;
    }
    {
      int k = tid >> 4, n4 = (tid & 15) << 2;
      float4 v = make_float4(0.f, 0.f, 0.f, 0.f);
      if (n0 + n4 < N) v = *(const float4*)(W + (long)(k0 + k) * ldw + n0 + n4);
      Bs[k][n4 + 0] = v.x; Bs[k][n4 + 1] = v.y;
      Bs[k][n4 + 2] = v.z; Bs[k][n4 + 3] = v.w;
    }
    __syncthreads();
#pragma unroll
    for (int kk = 0; kk < BK; ++kk) {
      float a[8], bb[4];
#pragma unroll
      for (int i = 0; i < 8; ++i) a[i] = As[kk][ty * 8 + i];
#pragma unroll
      for (int jn = 0; jn < 4; ++jn) bb[jn] = Bs[kk][tx * 4 + jn];
#pragma unroll
      for (int i = 0; i < 8; ++i)
#pragma unroll
        for (int jn = 0; jn < 4; ++jn) acc[i][jn] = fmaf(a[i], bb[jn], acc[i][jn]);
    }
    __syncthreads();
  }

  int n = n0 + tx * 4;
  if (n < N) {
#pragma unroll
    for (int i = 0; i < 8; ++i) {
      int m = m0 + ty * 8 + i;
      float4 v;
      float* vp = &v.x;
#pragma unroll
      for (int jn = 0; jn < 4; ++jn) {
        float val = acc[i][jn];
        if (EPI) val += bias[n + jn];
        if (EPI == 1) val = softplusf_(val);
        vp[jn] = val;
      }
      *(float4*)(C + (long)m * ldc + n) = v;
    }
  }
}

// ---------------- causal conv4 + silu --------------------------------------
__global__ __launch_bounds__(256) void conv_kernel(const float* __restrict__ UZ,
                                                   const float* __restrict__ Wconv,
                                                   const float* __restrict__ bconv,
                                                   float* __restrict__ uc, int stage) {
  long idx = (long)blockIdx.x * 256 + threadIdx.x;  // 8192*256
  int di = (int)(idx & 255);
  long r = idx >> 8;
  int l = (int)(r & 1023);
  int j = (int)(r >> 12);
  int lidx = stage + 2 * j;
  const float* wc = Wconv + (long)(lidx * 256 + di) * 4;
  float acc = bconv[lidx * 256 + di];
  const float* up = UZ + (r - 3) * 512 + di;
  if (l >= 3) {
    acc = fmaf(up[0], wc[0], acc);
    acc = fmaf(up[512], wc[1], acc);
    acc = fmaf(up[1024], wc[2], acc);
    acc = fmaf(up[1536], wc[3], acc);
  } else {
    for (int k = 3 - l; k < 4; ++k) acc = fmaf(up[(long)k * 512], wc[k], acc);
  }
  uc[idx] = acc * sigmoidf_(acc);
}

// ---------------- selective scan: chunked ----------------------------------
template <int PASS>
__global__ __launch_bounds__(256)
void scan_chunk_kernel(const float* __restrict__ dt,
                       const float* __restrict__ uc,
                       const float* __restrict__ UZ,
                       const float* __restrict__ proj,
                       const float* __restrict__ Aneg,
                       const float* __restrict__ Dskip,
                       float* __restrict__ HST,   // [8][NC][256][32]
                       float* __restrict__ DTS,   // [8][NC][256]
                       float* __restrict__ yg, int stage) {
  __shared__ __align__(16) float BC[SCAN_CL][64];
  const int blk = blockIdx.x;
  const int chunk = blk & (SCAN_NC - 1);
  const int jb = blk >> 6;
  const int di = threadIdx.x;
  const int j = jb >> 2;
  const int lidx = stage + 2 * j;
  const long r0 = (long)jb * 1024 + (long)chunk * SCAN_CL;

  for (int e = threadIdx.x; e < SCAN_CL * 64; e += 256) {
    int l = e >> 6, col = e & 63;
    BC[l][col] = proj[(r0 + l) * 80 + 16 + col];
  }

  float A[32];
  {
    const float4* ap = (const float4*)(Aneg + ((long)(lidx * 256 + di)) * 32);
#pragma unroll
    for (int q = 0; q < 8; ++q) {
      float4 v = ap[q];
      A[4 * q] = v.x; A[4 * q + 1] = v.y; A[4 * q + 2] = v.z; A[4 * q + 3] = v.w;
    }
  }

  const long sbase = (((long)jb * SCAN_NC + chunk) * 256 + di) * 32;
  float h[32];
  if (PASS == 0) {
#pragma unroll
    for (int n = 0; n < 32; ++n) h[n] = 0.f;
  } else {
    const float4* hp = (const float4*)(HST + sbase);
#pragma unroll
    for (int q = 0; q < 8; ++q) {
      float4 v = hp[q];
      h[4 * q] = v.x; h[4 * q + 1] = v.y; h[4 * q + 2] = v.z; h[4 * q + 3] = v.w;
    }
  }

  float Dsk = 0.f, dtsum = 0.f;
  if (PASS == 1) Dsk = Dskip[lidx * 256 + di];

  __syncthreads();

  for (int l = 0; l < SCAN_CL; ++l) {
    const long r = r0 + l;
    float dtv = dt[r * 256 + di];
    float uv  = uc[r * 256 + di];
    float du  = dtv * uv;
    if (PASS == 0) dtsum += dtv;
    float yacc[4] = {0.f, 0.f, 0.f, 0.f};
    const float4* bc4 = (const float4*)&BC[l][0];
#pragma unroll
    for (int q = 0; q < 8; ++q) {
      float4 bv = bc4[q];
      float4 cv = bc4[8 + q];
      const float* bp = &bv.x;
      const float* cp = &cv.x;
#pragma unroll
      for (int k = 0; k < 4; ++k) {
        int n = 4 * q + k;
        float a = __expf(dtv * A[n]);
        h[n] = fmaf(a, h[n], du * bp[k]);
        yacc[n & 3] = fmaf(h[n], cp[k], yacc[n & 3]);
      }
    }
    if (PASS == 1) {
      float y = (yacc[0] + yacc[1]) + (yacc[2] + yacc[3]);
      float zv = UZ[r * 512 + 256 + di];
      yg[r * 256 + di] = (y + uv * Dsk) * siluf_(zv);
    }
  }

  if (PASS == 0) {
    float4* hp = (float4*)(HST + sbase);
#pragma unroll
    for (int q = 0; q < 8; ++q)
      hp[q] = make_float4(h[4 * q], h[4 * q + 1], h[4 * q + 2], h[4 * q + 3]);
    DTS[((long)jb * SCAN_NC + chunk) * 256 + di] = dtsum;
  }
}

// ---------------- scan pass 2: sequential chunk combine --------------------
__global__ __launch_bounds__(256)
void scan_combine_kernel(float* __restrict__ HST, const float* __restrict__ DTS,
                         const float* __restrict__ Aneg, int stage) {
  int t = blockIdx.x * 256 + threadIdx.x;   // 65536
  int n = t & 31;
  int di = (t >> 5) & 255;
  int jb = t >> 13;
  int lidx = stage + 2 * (jb >> 2);
  float A = Aneg[((long)(lidx * 256 + di)) * 32 + n];
  float hs = 0.f;
  for (int c = 0; c < SCAN_NC; ++c) {
    long base = ((long)jb * SCAN_NC + c) * 256 + di;
    long idx = base * 32 + n;
    float s = HST[idx];
    HST[idx] = hs;
    float P = __expf(A * DTS[base]);
    hs = fmaf(P, hs, s);
  }
}

// ---------------- final combine --------------------------------------------
__global__ __launch_bounds__(256) void combine_kernel(const float* __restrict__ H,
                                                      const float* __restrict__ gate,
                                                      const float* __restrict__ alpha,
                                                      const float* __restrict__ gamma,
                                                      const float* __restrict__ beta,
                                                      float* __restrict__ out) {
  long idx = (long)blockIdx.x * 256 + threadIdx.x;  // 1,048,576 (b,d,l)
  int l = (int)(idx & 1023);
  long t = idx >> 10;
  int d = (int)(t & 255);
  int b = (int)(t >> 8);
  int lr = 1023 - l;
  float h0 = H[(((long)b * 1024 + l) * 256) + d];
  float h1 = H[(((long)(4 + b) * 1024 + lr) * 256) + d];
  float g0 = gate[((long)(b * 256 + d)) * 1024 + l];
  float g1 = gate[(long)1024 * 1024 + ((long)(b * 256 + d)) * 1024 + lr];
  float m0 = (gamma[l] * tanhf(alpha[0] * h0) + beta[l]) * g0;
  float m1 = (gamma[1024 + lr] * tanhf(alpha[1] * h1) + beta[1024 + lr]) * g1;
  out[idx] = m0 + m1;
}

// ---------------------------------------------------------------------------
extern "C" void kernel_launch(void* const* d_in, const int* in_sizes, int n_in,
                              void* d_out, int out_size, void* d_ws, size_t ws_size,
                              hipStream_t stream) {
  const float* x     = (const float*)d_in[0];
  const float* Win   = (const float*)d_in[1];
  const float* Wconv = (const float*)d_in[2];
  const float* bconv = (const float*)d_in[3];
  const float* Wxp   = (const float*)d_in[4];
  const float* Wdt   = (const float*)d_in[5];
  const float* bdt   = (const float*)d_in[6];
  const float* Alog  = (const float*)d_in[7];
  const float* Dskip = (const float*)d_in[8];
  const float* Wout  = (const float*)d_in[9];
  const float* Wg    = (const float*)d_in[10];
  const float* bg    = (const float*)d_in[11];
  const float* alpha = (const float*)d_in[12];
  const float* gamma = (const float*)d_in[13];
  const float* beta  = (const float*)d_in[14];
  float* out = (float*)d_out;

  float* ws   = (float*)d_ws;
  float* X    = ws;                    // 2,097,152 f
  float* YG   = X + 2097152;           // 2,097,152 f
  float* UZ   = YG + 2097152;          // 4,194,304 f
  float* UC   = UZ + 4194304;          // 2,097,152 f
  float* PROJ = UC + 2097152;          // 655,360 f
  float* DT   = PROJ + 655360;         // 2,097,152 f
  float* GATE = DT + 2097152;          // 2,097,152 f
  float* ANEG = GATE + 2097152;        // 32,768 f
  float* HST  = ANEG + 32768;          // 4,194,304 f
  float* DTS  = HST + 4194304;         // 131,072 f
  unsigned short* WinT3  = (unsigned short*)(DTS + 131072);  // 3 x 524,288 u16
  unsigned short* WoutT3 = WinT3 + 3 * 524288;               // 3 x 262,144 u16
  // total: 20,873,216 f-equiv = 83.5 MB
  unsigned short* WinTh = WinT3,  *WinTm = WinT3 + 524288,  *WinTl = WinT3 + 1048576;
  unsigned short* WoutTh = WoutT3, *WoutTm = WoutT3 + 262144, *WoutTl = WoutT3 + 524288;
  // Wg 3-split planes alias HST (dead until stage-0 scan, gate GEMM is earlier)
  unsigned short* Wgh = (unsigned short*)HST;     // 2,097,152 u16 each
  unsigned short* Wgm = Wgh + 2097152;
  unsigned short* Wgl = Wgm + 2097152;            // 12.6 MB <= HST's 16.8 MB

  prep_kernel<<<dim3(8192), dim3(256), 0, stream>>>(x, X);
  aneg_kernel<<<dim3(128), dim3(256), 0, stream>>>(Alog, ANEG);
  split3v_kernel<<<dim3(2048), dim3(256), 0, stream>>>(
      (const float4*)Wg, (ushort4*)Wgh, (ushort4*)Wgm, (ushort4*)Wgl, 524288);
  tconv3_kernel<<<dim3(16, 8, 4), dim3(256), 0, stream>>>(Win, WinTh, WinTm, WinTl, 256, 512);
  tconv3_kernel<<<dim3(8, 8, 4), dim3(256), 0, stream>>>(Wout, WoutTh, WoutTm, WoutTl, 256, 256);

  // gate: GATE[z] = sigmoid(x @ Wg[z]^T + bg[z]); A = x shared across z
  gemm_mfma<1><<<dim3(8, 8, 2), dim3(256), 0, stream>>>(
      x, 0L, Wgh, Wgm, Wgl, (long)1024 * 1024, bg, 1024L,
      GATE, (long)1024 * 1024, 1024, 1024);

  for (int s = 0; s < 2; ++s) {
    // GEMM1: UZ = X @ Win[lidx]  (N=512, K=256)
    gemm_mfma<0><<<dim3(4, 32, 2), dim3(256), 0, stream>>>(
        X, (long)4096 * 256,
        WinTh + (long)s * 131072, WinTm + (long)s * 131072, WinTl + (long)s * 131072,
        (long)2 * 131072, nullptr, 0L,
        UZ, (long)4096 * 512, 512, 256);

    conv_kernel<<<dim3(8192), dim3(256), 0, stream>>>(UZ, Wconv, bconv, UC, s);

    // GEMM2: PROJ = UC @ Wxp[lidx] (N=80)
    gemm_f32<0><<<dim3(2, 32, 2), dim3(256), 0, stream>>>(
        UC, 256, (long)4096 * 256, Wxp + (long)s * 256 * 80, 80, (long)2 * 256 * 80,
        nullptr, 0, PROJ, 80, (long)4096 * 80, 4096, 80, 256);

    // GEMM3: DT = softplus(PROJ[:, :16] @ Wdt[lidx] + bdt[lidx])
    gemm_f32<1><<<dim3(4, 32, 2), dim3(256), 0, stream>>>(
        PROJ, 80, (long)4096 * 80, Wdt + (long)s * 16 * 256, 256, (long)2 * 16 * 256,
        bdt + s * 256, 512, DT, 256, (long)4096 * 256, 4096, 256, 16);

    // chunked selective scan
    scan_chunk_kernel<0><<<dim3(8 * SCAN_NC), dim3(256), 0, stream>>>(
        DT, UC, UZ, PROJ, ANEG, Dskip, HST, DTS, YG, s);
    scan_combine_kernel<<<dim3(256), dim3(256), 0, stream>>>(HST, DTS, ANEG, s);
    scan_chunk_kernel<1><<<dim3(8 * SCAN_NC), dim3(256), 0, stream>>>(
        DT, UC, UZ, PROJ, ANEG, Dskip, HST, DTS, YG, s);

    // GEMM4: X = YG @ Wout[lidx]  (stage0 feeds stage1; stage1 = H)
    gemm_mfma<0><<<dim3(2, 32, 2), dim3(256), 0, stream>>>(
        YG, (long)4096 * 256,
        WoutTh + (long)s * 65536, WoutTm + (long)s * 65536, WoutTl + (long)s * 65536,
        (long)2 * 65536, nullptr, 0L,
        X, (long)4096 * 256, 256, 256);
  }

  combine_kernel<<<dim3(4096), dim3(256), 0, stream>>>(X, GATE, alpha, gamma, beta, out);
}